// Round 5
// baseline (1014.587 us; speedup 1.0000x reference)
//
#include <hip/hip_runtime.h>

#define EPS_ 1e-5f

typedef float f32x4 __attribute__((ext_vector_type(4)));
typedef short s16x8 __attribute__((ext_vector_type(8)));

static __device__ __forceinline__ short f2bf(float f) {
    unsigned u = __float_as_uint(f);
    unsigned r = (u + 0x7FFFu + ((u >> 16) & 1u)) >> 16;
    return (short)r;
}
static __device__ __forceinline__ float bf2f(short s) {
    return __uint_as_float(((unsigned)(unsigned short)s) << 16);
}

// ---------------------------------------------------------------------------
// Kernel 0: convert weight stacks to bf16 once.
// ---------------------------------------------------------------------------
__global__ __launch_bounds__(256) void prep_kernel(
    const float* __restrict__ Wq, const float* __restrict__ Wk,
    const float* __restrict__ Wv, const float* __restrict__ Wp,
    short* __restrict__ Wbf, short* __restrict__ Wpbf)
{
    int i = blockIdx.x * 256 + threadIdx.x;
    if (i < 6144) {
        float v = (i < 1024) ? Wq[i] : (i < 2048 ? Wk[i - 1024] : Wv[i - 2048]);
        Wbf[i] = f2bf(v);
    } else if (i < 6144 + 4096) {
        Wpbf[i - 6144] = f2bf(Wp[i - 6144]);
    }
}

// ---------------------------------------------------------------------------
// Kernel 1: QKV projection via MFMA + PReLU + LN(chan,freq), write bf16.
// ---------------------------------------------------------------------------
__global__ __launch_bounds__(256) void qkv_kernel(
    const float* __restrict__ x, const short* __restrict__ Wbf,
    const float* __restrict__ bq, const float* __restrict__ aq,
    const float* __restrict__ gq, const float* __restrict__ betq,
    const float* __restrict__ bk, const float* __restrict__ ak,
    const float* __restrict__ gk, const float* __restrict__ betk,
    const float* __restrict__ bv, const float* __restrict__ av,
    const float* __restrict__ gv, const float* __restrict__ betv,
    short* __restrict__ Qo, short* __restrict__ Ko, short* __restrict__ Vo)
{
    const int t = blockIdx.x;
    const int b = blockIdx.y;
    const int tid = threadIdx.x;
    const int wid = tid >> 6, lane = tid & 63;
    const int g = lane >> 4, c16 = lane & 15;
    const int f_ = tid & 63, cg = tid >> 6;

    __shared__ __align__(16) short wlds[96 * 64];
    __shared__ __align__(16) short xs[64 * 64];
    __shared__ float zs[96 * 64];
    __shared__ float stats[12][2];
    __shared__ float bias_l[96], alpha_l[96];

#pragma unroll
    for (int j = 0; j < 3; ++j) {
        int i8 = tid + 256 * j;
        int row = i8 >> 3, cb = i8 & 7;
        s16x8 v = *(const s16x8*)(Wbf + i8 * 8);
        *(s16x8*)&wlds[row * 64 + ((cb ^ (row & 7)) * 8)] = v;
    }
    if (tid < 96) {
        int row = tid; float bias, al;
        if (row < 16)      { bias = bq[row];      al = aq[row >> 2]; }
        else if (row < 32) { bias = bk[row - 16]; al = ak[(row - 16) >> 2]; }
        else               { bias = bv[row - 32]; al = av[(row - 32) >> 4]; }
        bias_l[row] = bias; alpha_l[row] = al;
    }
#pragma unroll
    for (int it = 0; it < 2; ++it) {
        int cb = cg + 4 * it, c0 = cb * 8;
        s16x8 v;
#pragma unroll
        for (int i = 0; i < 8; ++i)
            v[i] = f2bf(x[(((size_t)b * 64 + c0 + i) * 2048 + t) * 64 + f_]);
        *(s16x8*)&xs[f_ * 64 + ((cb ^ (f_ & 7)) * 8)] = v;
    }
    __syncthreads();

    const int f0 = wid * 16;
    s16x8 bfr[2];
#pragma unroll
    for (int kk = 0; kk < 2; ++kk)
        bfr[kk] = *(const s16x8*)&xs[(f0 + c16) * 64 + (((kk * 4 + g) ^ (c16 & 7)) * 8)];

    f32x4 acc[6];
#pragma unroll
    for (int rt = 0; rt < 6; ++rt) {
#pragma unroll
        for (int r = 0; r < 4; ++r) acc[rt][r] = 0.f;
#pragma unroll
        for (int kk = 0; kk < 2; ++kk) {
            s16x8 a = *(const s16x8*)&wlds[(rt * 16 + c16) * 64 + (((kk * 4 + g) ^ (c16 & 7)) * 8)];
            acc[rt] = __builtin_amdgcn_mfma_f32_16x16x32_bf16(a, bfr[kk], acc[rt], 0, 0, 0);
        }
    }

#pragma unroll
    for (int rt = 0; rt < 6; ++rt)
#pragma unroll
        for (int r = 0; r < 4; ++r) {
            int row = rt * 16 + g * 4 + r;
            float z = acc[rt][r] + bias_l[row];
            z = z >= 0.f ? z : alpha_l[row] * z;
            zs[row * 64 + f0 + c16] = z;
        }
    __syncthreads();

#pragma unroll
    for (int gi = 0; gi < 3; ++gi) {
        int grp = wid * 3 + gi;
        int base_row, n;
        if (grp < 4)      { base_row = grp * 4;             n = 256; }
        else if (grp < 8) { base_row = 16 + (grp - 4) * 4;  n = 256; }
        else              { base_row = 32 + (grp - 8) * 16; n = 1024; }
        int cnt = n >> 6;
        float s = 0.f, ss = 0.f;
        for (int i = 0; i < cnt; ++i) {
            float v = zs[(base_row + i) * 64 + lane];
            s += v; ss += v * v;
        }
#pragma unroll
        for (int msk = 32; msk >= 1; msk >>= 1) {
            s  += __shfl_xor(s, msk);
            ss += __shfl_xor(ss, msk);
        }
        if (lane == 0) {
            float mean = s / n;
            float var = ss / n - mean * mean;
            stats[grp][0] = mean;
            stats[grp][1] = rsqrtf(var + EPS_);
        }
    }
    __syncthreads();

#pragma unroll
    for (int j = 0; j < 24; ++j) {
        int row = cg + 4 * j;
        float zv = zs[row * 64 + f_];
        if (row < 16) {
            int grp = row >> 2;
            float val = (zv - stats[grp][0]) * stats[grp][1];
            val = val * gq[row * 64 + f_] + betq[row * 64 + f_];
            int h = row >> 2, o = row & 3;
            Qo[(((size_t)(h * 2 + b)) * 2048 + t) * 256 + o * 64 + f_] = f2bf(val);
        } else if (row < 32) {
            int rr = row - 16, grp = 4 + (rr >> 2);
            float val = (zv - stats[grp][0]) * stats[grp][1];
            val = val * gk[rr * 64 + f_] + betk[rr * 64 + f_];
            int h = rr >> 2, o = rr & 3;
            Ko[(((size_t)(h * 2 + b)) * 2048 + t) * 256 + o * 64 + f_] = f2bf(val);
        } else {
            int rr = row - 32, grp = 8 + (rr >> 4);
            float val = (zv - stats[grp][0]) * stats[grp][1];
            val = val * gv[rr * 64 + f_] + betv[rr * 64 + f_];
            int h = rr >> 4, ov = rr & 15;
            Vo[(((size_t)(h * 2 + b)) * 2048 + t) * 1024 + ov * 64 + f_] = f2bf(val);
        }
    }
}

// ---------------------------------------------------------------------------
// Kernel 2: V row-major [hb][t][d] -> V^T [hb][d][t]
// ---------------------------------------------------------------------------
__global__ __launch_bounds__(256) void vtrans_kernel(
    const short* __restrict__ Vrm, short* __restrict__ Vt)
{
    const int t0 = blockIdx.x * 64;
    const int d0 = blockIdx.y * 64;
    const int hb = blockIdx.z;
    const int tid = threadIdx.x;
    __shared__ __align__(16) short tile[64 * 72];

#pragma unroll
    for (int k = 0; k < 2; ++k) {
        int q = tid + 256 * k;
        int row = q >> 3, slot = q & 7;
        s16x8 v = *(const s16x8*)(Vrm + ((size_t)hb * 2048 + t0 + row) * 1024 + d0 + slot * 8);
        *(s16x8*)&tile[row * 72 + slot * 8] = v;
    }
    __syncthreads();
#pragma unroll
    for (int k = 0; k < 2; ++k) {
        int q = tid + 256 * k;
        int drow = q >> 3, tslot = q & 7;
        s16x8 v;
#pragma unroll
        for (int i = 0; i < 8; ++i)
            v[i] = tile[(tslot * 8 + i) * 72 + drow];
        *(s16x8*)(Vt + ((size_t)hb * 1024 + d0 + drow) * 2048 + t0 + tslot * 8) = v;
    }
}

// ---------------------------------------------------------------------------
// Kernel 3: flash attention, QBLK=32 -> 512 blocks (2 blocks/CU for overlap).
// Grid (hb, qt): linear%8 == hb -> XCD-affine (each XCD keeps one head's K/V).
// 8 waves: QK^T role (qs = wid&1: 16 q-rows; kq = wid>>1: 16-key quarter);
// PV role (d-slice [wid*128,+128) for all 32 q-rows; V loaded once/block).
// No-max softmax (Q,K LayerNorm'd -> |S*scale| small). K: LDS dbuf,
// reg-staged (load early, ds_write late). 2 barriers/tile.
// ---------------------------------------------------------------------------
__global__ __launch_bounds__(512, 4) void attn_kernel(
    const short* __restrict__ Qg, const short* __restrict__ Kg,
    const short* __restrict__ Vt, short* __restrict__ Ob)
{
    const int hb = blockIdx.x;
    const int qt = blockIdx.y;     // 0..63
    const int t0 = qt * 32;
    const int tid = threadIdx.x;
    const int lane = tid & 63;
    const int wid = tid >> 6;
    const int qs = wid & 1;        // q-stripe for QK^T
    const int kq = wid >> 1;       // key-quarter for QK^T
    const int g = lane >> 4, c16 = lane & 15;

    __shared__ __align__(16) short k_lds[2][64 * 256];   // 64 KB dbuf
    __shared__ __align__(16) short p_lds[32 * 72];       // 4.5 KB
    __shared__ float lpart[4][32];

    // Q fragments for stripe qs (16 rows x 256 d)
    const size_t qbase = ((size_t)hb * 2048 + t0 + qs * 16 + c16) * 256;
    s16x8 qf[8];
#pragma unroll
    for (int kf = 0; kf < 8; ++kf)
        qf[kf] = *(const s16x8*)(Qg + qbase + kf * 32 + g * 8);

    f32x4 oacc[16];                // [dt 0..7][s4 0..1]
#pragma unroll
    for (int i = 0; i < 16; ++i)
#pragma unroll
        for (int r = 0; r < 4; ++r) oacc[i][r] = 0.f;

    float l_r[4] = {0.f, 0.f, 0.f, 0.f};

    // K staging decomposition: 2048 16B-chunks, 4 per thread
    // prologue: stage K tile 0
    {
        s16x8 kreg0[4];
#pragma unroll
        for (int j = 0; j < 4; ++j) {
            int q_ = tid + 512 * j;
            int row = q_ >> 5, slot = q_ & 31;
            kreg0[j] = *(const s16x8*)(Kg + ((size_t)hb * 2048 + row) * 256 + slot * 8);
        }
#pragma unroll
        for (int j = 0; j < 4; ++j) {
            int q_ = tid + 512 * j;
            int row = q_ >> 5, slot = q_ & 31;
            *(s16x8*)&k_lds[0][row * 256 + ((slot ^ (row & 7)) * 8)] = kreg0[j];
        }
    }
    __syncthreads();

    const int dsl = wid * 128;     // this wave's V d-slice
    const size_t vrow0 = (size_t)hb * 1024 + dsl + c16;

    for (int tile = 0; tile < 32; ++tile) {
        const int cur = tile & 1;
        const int kt0 = tile * 64;

        // issue next K tile loads early
        s16x8 kreg[4];
        if (tile < 31) {
#pragma unroll
            for (int j = 0; j < 4; ++j) {
                int q_ = tid + 512 * j;
                int row = q_ >> 5, slot = q_ & 31;
                kreg[j] = *(const s16x8*)(Kg + ((size_t)hb * 2048 + kt0 + 64 + row) * 256 + slot * 8);
            }
        }

        // QK^T: 16 q-rows x 16 keys per wave, K=256 (8 MFMA)
        f32x4 sf;
#pragma unroll
        for (int r = 0; r < 4; ++r) sf[r] = 0.f;
        const int krow = kq * 16 + c16;
        __builtin_amdgcn_s_setprio(1);
#pragma unroll
        for (int kf = 0; kf < 8; ++kf) {
            s16x8 kb = *(const s16x8*)&k_lds[cur][krow * 256 + (((kf * 4 + g) ^ (krow & 7)) * 8)];
            sf = __builtin_amdgcn_mfma_f32_16x16x32_bf16(qf[kf], kb, sf, 0, 0, 0);
        }
        __builtin_amdgcn_s_setprio(0);

        // exp (no max) + partial row sums over this key-quarter
        float rs[4];
#pragma unroll
        for (int r = 0; r < 4; ++r) {
            float p = __expf(sf[r] * 0.0625f);
            sf[r] = p;
            rs[r] = p;
        }
#pragma unroll
        for (int msk = 1; msk <= 8; msk <<= 1)
#pragma unroll
            for (int r = 0; r < 4; ++r) rs[r] += __shfl_xor(rs[r], msk);
#pragma unroll
        for (int r = 0; r < 4; ++r) l_r[r] += rs[r];

        // write this wave's P quarter (bf16)
#pragma unroll
        for (int r = 0; r < 4; ++r)
            p_lds[(qs * 16 + g * 4 + r) * 72 + kq * 16 + c16] = f2bf(sf[r]);

        __syncthreads();   // barrier 1: P visible; k_lds[cur] reads done

        // P A-fragments for both q-stripes
        s16x8 pa[2][2];
#pragma unroll
        for (int s4 = 0; s4 < 2; ++s4)
#pragma unroll
            for (int ks = 0; ks < 2; ++ks)
                pa[s4][ks] = *(const s16x8*)&p_lds[(s4 * 16 + c16) * 72 + ks * 32 + g * 8];

        // V: issue all 16 fragment loads up-front (deep VMEM queue)
        s16x8 vf[8][2];
#pragma unroll
        for (int dt = 0; dt < 8; ++dt)
#pragma unroll
            for (int ks = 0; ks < 2; ++ks)
                vf[dt][ks] = *(const s16x8*)(Vt + (vrow0 + dt * 16) * 2048 + kt0 + (ks * 4 + g) * 8);

        // PV: 8 d-tiles x 2 stripes x 2 ks (32 MFMA)
        __builtin_amdgcn_s_setprio(1);
#pragma unroll
        for (int dt = 0; dt < 8; ++dt)
#pragma unroll
            for (int s4 = 0; s4 < 2; ++s4)
#pragma unroll
                for (int ks = 0; ks < 2; ++ks)
                    oacc[dt * 2 + s4] = __builtin_amdgcn_mfma_f32_16x16x32_bf16(
                        pa[s4][ks], vf[dt][ks], oacc[dt * 2 + s4], 0, 0, 0);
        __builtin_amdgcn_s_setprio(0);

        // write next K tile into the other LDS buffer
        if (tile < 31) {
#pragma unroll
            for (int j = 0; j < 4; ++j) {
                int q_ = tid + 512 * j;
                int row = q_ >> 5, slot = q_ & 31;
                *(s16x8*)&k_lds[cur ^ 1][row * 256 + ((slot ^ (row & 7)) * 8)] = kreg[j];
            }
        }
        __syncthreads();   // barrier 2: next K staged; p_lds reads done
    }

    // combine softmax denominators across the 4 key-quarter waves
    if (c16 == 0) {
#pragma unroll
        for (int r = 0; r < 4; ++r)
            lpart[kq][qs * 16 + g * 4 + r] = l_r[r];
    }
    __syncthreads();

    float li[8];                   // [s4][r]
#pragma unroll
    for (int s4 = 0; s4 < 2; ++s4)
#pragma unroll
        for (int r = 0; r < 4; ++r) {
            int row = s4 * 16 + g * 4 + r;
            li[s4 * 4 + r] = 1.f / (lpart[0][row] + lpart[1][row] + lpart[2][row] + lpart[3][row]);
        }

    // epilogue: O /= l, write bf16 in [b][h*16+ov][t][f] layout
    const int h = hb >> 1, b = hb & 1;
#pragma unroll
    for (int dt = 0; dt < 8; ++dt) {
        int vcol = dsl + dt * 16 + c16;
        int cout = h * 16 + (vcol >> 6), ff = vcol & 63;
#pragma unroll
        for (int s4 = 0; s4 < 2; ++s4)
#pragma unroll
            for (int r = 0; r < 4; ++r) {
                int trow = t0 + s4 * 16 + g * 4 + r;
                Ob[(((size_t)b * 64 + cout) * 2048 + trow) * 64 + ff] =
                    f2bf(oacc[dt * 2 + s4][r] * li[s4 * 4 + r]);
            }
    }
}

// ---------------------------------------------------------------------------
// Kernel 4: output projection via MFMA + PReLU + LN(C,F) + residual
// ---------------------------------------------------------------------------
__global__ __launch_bounds__(256) void oproj_kernel(
    const short* __restrict__ Ob, const float* __restrict__ x,
    const short* __restrict__ Wpbf,
    const float* __restrict__ bp, const float* __restrict__ ap,
    const float* __restrict__ gp, const float* __restrict__ betp,
    float* __restrict__ out)
{
    const int t = blockIdx.x;
    const int b = blockIdx.y;
    const int tid = threadIdx.x;
    const int wid = tid >> 6, lane = tid & 63;
    const int g = lane >> 4, c16 = lane & 15;
    const int f_ = tid & 63, cg = tid >> 6;

    __shared__ __align__(16) short wp[64 * 64];
    __shared__ __align__(16) short os[64 * 64];
    __shared__ float zs[64 * 64];
    __shared__ float red[4][2];

#pragma unroll
    for (int j = 0; j < 2; ++j) {
        int i8 = tid + 256 * j;
        int row = i8 >> 3, cb = i8 & 7;
        s16x8 v = *(const s16x8*)(Wpbf + i8 * 8);
        *(s16x8*)&wp[row * 64 + ((cb ^ (row & 7)) * 8)] = v;
    }
#pragma unroll
    for (int it = 0; it < 2; ++it) {
        int cb = cg + 4 * it, c0 = cb * 8;
        s16x8 v;
#pragma unroll
        for (int i = 0; i < 8; ++i)
            v[i] = Ob[(((size_t)b * 64 + c0 + i) * 2048 + t) * 64 + f_];
        *(s16x8*)&os[f_ * 64 + ((cb ^ (f_ & 7)) * 8)] = v;
    }
    __syncthreads();

    const int f0 = wid * 16;
    s16x8 bfr[2];
#pragma unroll
    for (int kk = 0; kk < 2; ++kk)
        bfr[kk] = *(const s16x8*)&os[(f0 + c16) * 64 + (((kk * 4 + g) ^ (c16 & 7)) * 8)];

    const float ap0 = ap[0];
    f32x4 acc[4];
#pragma unroll
    for (int rt = 0; rt < 4; ++rt) {
#pragma unroll
        for (int r = 0; r < 4; ++r) acc[rt][r] = 0.f;
#pragma unroll
        for (int kk = 0; kk < 2; ++kk) {
            s16x8 a = *(const s16x8*)&wp[(rt * 16 + c16) * 64 + (((kk * 4 + g) ^ (c16 & 7)) * 8)];
            acc[rt] = __builtin_amdgcn_mfma_f32_16x16x32_bf16(a, bfr[kk], acc[rt], 0, 0, 0);
        }
    }

#pragma unroll
    for (int rt = 0; rt < 4; ++rt)
#pragma unroll
        for (int r = 0; r < 4; ++r) {
            int row = rt * 16 + g * 4 + r;
            float z = acc[rt][r] + bp[row];
            z = z >= 0.f ? z : ap0 * z;
            zs[row * 64 + f0 + c16] = z;
        }
    __syncthreads();

    float s = 0.f, ss = 0.f;
#pragma unroll
    for (int j = 0; j < 16; ++j) {
        float v = zs[(cg + 4 * j) * 64 + f_];
        s += v; ss += v * v;
    }
#pragma unroll
    for (int msk = 32; msk >= 1; msk >>= 1) {
        s  += __shfl_xor(s, msk);
        ss += __shfl_xor(ss, msk);
    }
    if (lane == 0) { red[wid][0] = s; red[wid][1] = ss; }
    __syncthreads();
    float ts  = red[0][0] + red[1][0] + red[2][0] + red[3][0];
    float tss = red[0][1] + red[1][1] + red[2][1] + red[3][1];
    float mean = ts * (1.f / 4096.f);
    float rstd = rsqrtf(tss * (1.f / 4096.f) - mean * mean + EPS_);

#pragma unroll
    for (int j = 0; j < 16; ++j) {
        int row = cg + 4 * j;
        size_t idx = (((size_t)b * 64 + row) * 2048 + t) * 64 + f_;
        out[idx] = (zs[row * 64 + f_] - mean) * rstd * gp[row * 64 + f_]
                 + betp[row * 64 + f_] + x[idx];
    }
}

// ---------------------------------------------------------------------------
extern "C" void kernel_launch(void* const* d_in, const int* in_sizes, int n_in,
                              void* d_out, int out_size, void* d_ws, size_t ws_size,
                              hipStream_t stream)
{
    const float* x    = (const float*)d_in[0];
    const float* Wq   = (const float*)d_in[1];
    const float* bq   = (const float*)d_in[2];
    const float* aq   = (const float*)d_in[3];
    const float* gq   = (const float*)d_in[4];
    const float* betq = (const float*)d_in[5];
    const float* Wk   = (const float*)d_in[6];
    const float* bk   = (const float*)d_in[7];
    const float* ak   = (const float*)d_in[8];
    const float* gk   = (const float*)d_in[9];
    const float* betk = (const float*)d_in[10];
    const float* Wv   = (const float*)d_in[11];
    const float* bv   = (const float*)d_in[12];
    const float* av   = (const float*)d_in[13];
    const float* gv   = (const float*)d_in[14];
    const float* betv = (const float*)d_in[15];
    const float* Wp   = (const float*)d_in[16];
    const float* bp   = (const float*)d_in[17];
    const float* ap   = (const float*)d_in[18];
    const float* gp   = (const float*)d_in[19];
    const float* betp = (const float*)d_in[20];

    short* Qb   = (short*)d_ws;
    short* Kb   = Qb   + (size_t)8 * 2048 * 256;
    short* Vrm  = Kb   + (size_t)8 * 2048 * 256;
    short* Vt   = Vrm  + (size_t)8 * 2048 * 1024;
    short* Obuf = Vt   + (size_t)8 * 2048 * 1024;
    short* Wbf  = Obuf + (size_t)8 * 2048 * 1024;
    short* Wpbf = Wbf  + 96 * 64;

    prep_kernel<<<40, 256, 0, stream>>>(Wq, Wk, Wv, Wp, Wbf, Wpbf);
    qkv_kernel<<<dim3(2048, 2), 256, 0, stream>>>(x, Wbf,
        bq, aq, gq, betq, bk, ak, gk, betk, bv, av, gv, betv, Qb, Kb, Vrm);
    vtrans_kernel<<<dim3(32, 16, 8), 256, 0, stream>>>(Vrm, Vt);
    attn_kernel<<<dim3(8, 64), 512, 0, stream>>>(Qb, Kb, Vt, Obuf);
    oproj_kernel<<<dim3(2048, 2), 256, 0, stream>>>(Obuf, x, Wpbf,
        bp, ap, gp, betp, (float*)d_out);
}

// Round 6
// 265.113 us; speedup vs baseline: 3.8270x; 3.8270x over previous
//
#include <hip/hip_runtime.h>

#define EPS_ 1e-5f

typedef float f32x4 __attribute__((ext_vector_type(4)));
typedef short s16x8 __attribute__((ext_vector_type(8)));

static __device__ __forceinline__ short f2bf(float f) {
    unsigned u = __float_as_uint(f);
    unsigned r = (u + 0x7FFFu + ((u >> 16) & 1u)) >> 16;
    return (short)r;
}
static __device__ __forceinline__ float bf2f(short s) {
    return __uint_as_float(((unsigned)(unsigned short)s) << 16);
}

// async global->LDS, 16B per lane, wave-uniform LDS base
static __device__ __forceinline__ void gload16(const short* g, short* l) {
    __builtin_amdgcn_global_load_lds(
        (const __attribute__((address_space(1))) unsigned int*)g,
        (__attribute__((address_space(3))) unsigned int*)l, 16, 0, 0);
}

// ---------------------------------------------------------------------------
// Kernel 0: convert weight stacks to bf16 once.
// ---------------------------------------------------------------------------
__global__ __launch_bounds__(256) void prep_kernel(
    const float* __restrict__ Wq, const float* __restrict__ Wk,
    const float* __restrict__ Wv, const float* __restrict__ Wp,
    short* __restrict__ Wbf, short* __restrict__ Wpbf)
{
    int i = blockIdx.x * 256 + threadIdx.x;
    if (i < 6144) {
        float v = (i < 1024) ? Wq[i] : (i < 2048 ? Wk[i - 1024] : Wv[i - 2048]);
        Wbf[i] = f2bf(v);
    } else if (i < 6144 + 4096) {
        Wpbf[i - 6144] = f2bf(Wp[i - 6144]);
    }
}

// ---------------------------------------------------------------------------
// Kernel 1: QKV projection via MFMA + PReLU + LN(chan,freq), write bf16.
// ---------------------------------------------------------------------------
__global__ __launch_bounds__(256) void qkv_kernel(
    const float* __restrict__ x, const short* __restrict__ Wbf,
    const float* __restrict__ bq, const float* __restrict__ aq,
    const float* __restrict__ gq, const float* __restrict__ betq,
    const float* __restrict__ bk, const float* __restrict__ ak,
    const float* __restrict__ gk, const float* __restrict__ betk,
    const float* __restrict__ bv, const float* __restrict__ av,
    const float* __restrict__ gv, const float* __restrict__ betv,
    short* __restrict__ Qo, short* __restrict__ Ko, short* __restrict__ Vo)
{
    const int t = blockIdx.x;
    const int b = blockIdx.y;
    const int tid = threadIdx.x;
    const int wid = tid >> 6, lane = tid & 63;
    const int g = lane >> 4, c16 = lane & 15;
    const int f_ = tid & 63, cg = tid >> 6;

    __shared__ __align__(16) short wlds[96 * 64];
    __shared__ __align__(16) short xs[64 * 64];
    __shared__ float zs[96 * 64];
    __shared__ float stats[12][2];
    __shared__ float bias_l[96], alpha_l[96];

#pragma unroll
    for (int j = 0; j < 3; ++j) {
        int i8 = tid + 256 * j;
        int row = i8 >> 3, cb = i8 & 7;
        s16x8 v = *(const s16x8*)(Wbf + i8 * 8);
        *(s16x8*)&wlds[row * 64 + ((cb ^ (row & 7)) * 8)] = v;
    }
    if (tid < 96) {
        int row = tid; float bias, al;
        if (row < 16)      { bias = bq[row];      al = aq[row >> 2]; }
        else if (row < 32) { bias = bk[row - 16]; al = ak[(row - 16) >> 2]; }
        else               { bias = bv[row - 32]; al = av[(row - 32) >> 4]; }
        bias_l[row] = bias; alpha_l[row] = al;
    }
#pragma unroll
    for (int it = 0; it < 2; ++it) {
        int cb = cg + 4 * it, c0 = cb * 8;
        s16x8 v;
#pragma unroll
        for (int i = 0; i < 8; ++i)
            v[i] = f2bf(x[(((size_t)b * 64 + c0 + i) * 2048 + t) * 64 + f_]);
        *(s16x8*)&xs[f_ * 64 + ((cb ^ (f_ & 7)) * 8)] = v;
    }
    __syncthreads();

    const int f0 = wid * 16;
    s16x8 bfr[2];
#pragma unroll
    for (int kk = 0; kk < 2; ++kk)
        bfr[kk] = *(const s16x8*)&xs[(f0 + c16) * 64 + (((kk * 4 + g) ^ (c16 & 7)) * 8)];

    f32x4 acc[6];
#pragma unroll
    for (int rt = 0; rt < 6; ++rt) {
#pragma unroll
        for (int r = 0; r < 4; ++r) acc[rt][r] = 0.f;
#pragma unroll
        for (int kk = 0; kk < 2; ++kk) {
            s16x8 a = *(const s16x8*)&wlds[(rt * 16 + c16) * 64 + (((kk * 4 + g) ^ (c16 & 7)) * 8)];
            acc[rt] = __builtin_amdgcn_mfma_f32_16x16x32_bf16(a, bfr[kk], acc[rt], 0, 0, 0);
        }
    }

#pragma unroll
    for (int rt = 0; rt < 6; ++rt)
#pragma unroll
        for (int r = 0; r < 4; ++r) {
            int row = rt * 16 + g * 4 + r;
            float z = acc[rt][r] + bias_l[row];
            z = z >= 0.f ? z : alpha_l[row] * z;
            zs[row * 64 + f0 + c16] = z;
        }
    __syncthreads();

#pragma unroll
    for (int gi = 0; gi < 3; ++gi) {
        int grp = wid * 3 + gi;
        int base_row, n;
        if (grp < 4)      { base_row = grp * 4;             n = 256; }
        else if (grp < 8) { base_row = 16 + (grp - 4) * 4;  n = 256; }
        else              { base_row = 32 + (grp - 8) * 16; n = 1024; }
        int cnt = n >> 6;
        float s = 0.f, ss = 0.f;
        for (int i = 0; i < cnt; ++i) {
            float v = zs[(base_row + i) * 64 + lane];
            s += v; ss += v * v;
        }
#pragma unroll
        for (int msk = 32; msk >= 1; msk >>= 1) {
            s  += __shfl_xor(s, msk);
            ss += __shfl_xor(ss, msk);
        }
        if (lane == 0) {
            float mean = s / n;
            float var = ss / n - mean * mean;
            stats[grp][0] = mean;
            stats[grp][1] = rsqrtf(var + EPS_);
        }
    }
    __syncthreads();

#pragma unroll
    for (int j = 0; j < 24; ++j) {
        int row = cg + 4 * j;
        float zv = zs[row * 64 + f_];
        if (row < 16) {
            int grp = row >> 2;
            float val = (zv - stats[grp][0]) * stats[grp][1];
            val = val * gq[row * 64 + f_] + betq[row * 64 + f_];
            int h = row >> 2, o = row & 3;
            Qo[(((size_t)(h * 2 + b)) * 2048 + t) * 256 + o * 64 + f_] = f2bf(val);
        } else if (row < 32) {
            int rr = row - 16, grp = 4 + (rr >> 2);
            float val = (zv - stats[grp][0]) * stats[grp][1];
            val = val * gk[rr * 64 + f_] + betk[rr * 64 + f_];
            int h = rr >> 2, o = rr & 3;
            Ko[(((size_t)(h * 2 + b)) * 2048 + t) * 256 + o * 64 + f_] = f2bf(val);
        } else {
            int rr = row - 32, grp = 8 + (rr >> 4);
            float val = (zv - stats[grp][0]) * stats[grp][1];
            val = val * gv[rr * 64 + f_] + betv[rr * 64 + f_];
            int h = rr >> 4, ov = rr & 15;
            Vo[(((size_t)(h * 2 + b)) * 2048 + t) * 1024 + ov * 64 + f_] = f2bf(val);
        }
    }
}

// ---------------------------------------------------------------------------
// Kernel 2: V row-major [hb][t][d] -> V^T [hb][d][t]
// ---------------------------------------------------------------------------
__global__ __launch_bounds__(256) void vtrans_kernel(
    const short* __restrict__ Vrm, short* __restrict__ Vt)
{
    const int t0 = blockIdx.x * 64;
    const int d0 = blockIdx.y * 64;
    const int hb = blockIdx.z;
    const int tid = threadIdx.x;
    __shared__ __align__(16) short tile[64 * 72];

#pragma unroll
    for (int k = 0; k < 2; ++k) {
        int q = tid + 256 * k;
        int row = q >> 3, slot = q & 7;
        s16x8 v = *(const s16x8*)(Vrm + ((size_t)hb * 2048 + t0 + row) * 1024 + d0 + slot * 8);
        *(s16x8*)&tile[row * 72 + slot * 8] = v;
    }
    __syncthreads();
#pragma unroll
    for (int k = 0; k < 2; ++k) {
        int q = tid + 256 * k;
        int drow = q >> 3, tslot = q & 7;
        s16x8 v;
#pragma unroll
        for (int i = 0; i < 8; ++i)
            v[i] = tile[(tslot * 8 + i) * 72 + drow];
        *(s16x8*)(Vt + ((size_t)hb * 1024 + d0 + drow) * 2048 + t0 + tslot * 8) = v;
    }
}

// ---------------------------------------------------------------------------
// Kernel 3: flash attention, QBLK=64, one barrier per K-tile (pipelined).
// 8 waves. QK^T role: qs=wid>>1 (16-row stripe) x kp=wid&1 (32-key half).
// PV role: d-slice [wid*128,+128) for all 64 q-rows.
// Iter t: issue V(t) prefetch; DMA-stage K(t+2); QK^T(t+1) -> p[(t+1)&1];
//         PV(t) from p[t&1] with ring-2 V regs; barrier.
// K staged via global_load_lds (linear LDS dest, per-lane pre-swizzled src).
// ---------------------------------------------------------------------------
__global__ __launch_bounds__(512, 2) void attn_kernel(
    const short* __restrict__ Qg, const short* __restrict__ Kg,
    const short* __restrict__ Vt, short* __restrict__ Ob)
{
    const int hb = blockIdx.x;
    const int qt = blockIdx.y;     // 0..31
    const int t0 = qt * 64;
    const int tid = threadIdx.x;
    const int lane = tid & 63;
    const int wid = tid >> 6;
    const int qs = wid >> 1;       // q-stripe (QK^T)
    const int kp = wid & 1;        // key-half (QK^T)
    const int g = lane >> 4, c16 = lane & 15;

    __shared__ __align__(16) short k_lds[2][64 * 256];   // 64 KB dbuf
    __shared__ __align__(16) short p_lds[2][64 * 68];    // 17 KB dbuf
    __shared__ float lpart[2][64];

    const size_t qbase = ((size_t)hb * 2048 + t0 + qs * 16 + c16) * 256;
    const int dsl = wid * 128;
    const size_t vrow0 = (size_t)hb * 1024 + dsl + c16;
    const size_t kgbase = (size_t)hb * 2048 * 256;

    f32x4 oacc[32];
#pragma unroll
    for (int i = 0; i < 32; ++i)
#pragma unroll
        for (int r = 0; r < 4; ++r) oacc[i][r] = 0.f;

    float l_r[4] = {0.f, 0.f, 0.f, 0.f};

    // DMA-stage K tile kt into k_lds[buf]: 2048 16B chunks, swizzled source
#define STAGE_K(buf, kt) do {                                                  \
    _Pragma("unroll")                                                          \
    for (int j_ = 0; j_ < 4; ++j_) {                                           \
        int c_ = (wid * 4 + j_) * 64 + lane;                                   \
        int row_ = c_ >> 5, sp_ = c_ & 31;                                     \
        int slot_ = sp_ ^ (row_ & 7);                                          \
        gload16(Kg + kgbase + (size_t)((kt) * 64 + row_) * 256 + slot_ * 8,    \
                &k_lds[buf][(wid * 4 + j_) * 512]);                            \
    }                                                                          \
} while (0)

    // QK^T for tile nt: 16 q x 32 keys per wave, K=256; exp; l; write p[nt&1]
#define QKT_PHASE(nt) do {                                                     \
    s16x8 qf[8];                                                               \
    _Pragma("unroll")                                                          \
    for (int kf = 0; kf < 8; ++kf)                                             \
        qf[kf] = *(const s16x8*)(Qg + qbase + kf * 32 + g * 8);                \
    f32x4 sf[2];                                                               \
    _Pragma("unroll")                                                          \
    for (int nf = 0; nf < 2; ++nf)                                             \
        _Pragma("unroll")                                                      \
        for (int r = 0; r < 4; ++r) sf[nf][r] = 0.f;                           \
    __builtin_amdgcn_s_setprio(1);                                             \
    _Pragma("unroll")                                                          \
    for (int kf = 0; kf < 8; ++kf) {                                           \
        _Pragma("unroll")                                                      \
        for (int nf = 0; nf < 2; ++nf) {                                       \
            int krow = kp * 32 + nf * 16 + c16;                                \
            s16x8 kb = *(const s16x8*)&k_lds[(nt) & 1]                         \
                [krow * 256 + (((kf * 4 + g) ^ (krow & 7)) * 8)];              \
            sf[nf] = __builtin_amdgcn_mfma_f32_16x16x32_bf16(qf[kf], kb, sf[nf], 0, 0, 0); \
        }                                                                      \
    }                                                                          \
    __builtin_amdgcn_s_setprio(0);                                             \
    float rs[4] = {0.f, 0.f, 0.f, 0.f};                                        \
    _Pragma("unroll")                                                          \
    for (int nf = 0; nf < 2; ++nf)                                             \
        _Pragma("unroll")                                                      \
        for (int r = 0; r < 4; ++r) {                                          \
            float p = __expf(sf[nf][r] * 0.0625f);                             \
            sf[nf][r] = p;                                                     \
            rs[r] += p;                                                        \
        }                                                                      \
    _Pragma("unroll")                                                          \
    for (int msk = 1; msk <= 8; msk <<= 1)                                     \
        _Pragma("unroll")                                                      \
        for (int r = 0; r < 4; ++r) rs[r] += __shfl_xor(rs[r], msk);           \
    _Pragma("unroll")                                                          \
    for (int r = 0; r < 4; ++r) l_r[r] += rs[r];                               \
    _Pragma("unroll")                                                          \
    for (int nf = 0; nf < 2; ++nf)                                             \
        _Pragma("unroll")                                                      \
        for (int r = 0; r < 4; ++r)                                            \
            p_lds[(nt) & 1][(qs * 16 + g * 4 + r) * 68 + kp * 32 + nf * 16 + c16] \
                = f2bf(sf[nf][r]);                                             \
} while (0)

    // prologue
    STAGE_K(0, 0);
    __syncthreads();
    STAGE_K(1, 1);          // async, overlaps QK^T(0)
    QKT_PHASE(0);
    __syncthreads();

    for (int t = 0; t < 32; ++t) {
        const int kt0 = t * 64;

        // V prefetch for dt 0,1 (ring-2)
        s16x8 vf[2][2];
#pragma unroll
        for (int dt = 0; dt < 2; ++dt)
#pragma unroll
            for (int ks = 0; ks < 2; ++ks)
                vf[dt][ks] = *(const s16x8*)(Vt + (vrow0 + dt * 16) * 2048 + kt0 + (ks * 4 + g) * 8);

        if (t < 30) STAGE_K(t & 1, t + 2);
        if (t < 31) QKT_PHASE(t + 1);

        // P A-fragments for all 4 q-stripes (from p[t&1])
        s16x8 pa[4][2];
#pragma unroll
        for (int s4 = 0; s4 < 4; ++s4)
#pragma unroll
            for (int ks = 0; ks < 2; ++ks)
                pa[s4][ks] = *(const s16x8*)&p_lds[t & 1][(s4 * 16 + c16) * 68 + ks * 32 + g * 8];

        // PV: 8 d-tiles x 4 stripes x 2 ks, ring-2 register V
#pragma unroll
        for (int dt = 0; dt < 8; ++dt) {
            __builtin_amdgcn_s_setprio(1);
#pragma unroll
            for (int s4 = 0; s4 < 4; ++s4)
#pragma unroll
                for (int ks = 0; ks < 2; ++ks)
                    oacc[dt * 4 + s4] = __builtin_amdgcn_mfma_f32_16x16x32_bf16(
                        pa[s4][ks], vf[dt & 1][ks], oacc[dt * 4 + s4], 0, 0, 0);
            __builtin_amdgcn_s_setprio(0);
            if (dt < 6) {
#pragma unroll
                for (int ks = 0; ks < 2; ++ks)
                    vf[dt & 1][ks] = *(const s16x8*)(Vt + (vrow0 + (dt + 2) * 16) * 2048 + kt0 + (ks * 4 + g) * 8);
            }
        }

        if (t < 31) __syncthreads();
    }

#undef STAGE_K
#undef QKT_PHASE

    // combine softmax denominators across the two key-half waves
    __syncthreads();
    if (c16 == 0) {
#pragma unroll
        for (int r = 0; r < 4; ++r)
            lpart[kp][qs * 16 + g * 4 + r] = l_r[r];
    }
    __syncthreads();

    float li[16];
#pragma unroll
    for (int s4 = 0; s4 < 4; ++s4)
#pragma unroll
        for (int r = 0; r < 4; ++r) {
            int row = s4 * 16 + g * 4 + r;
            li[s4 * 4 + r] = 1.f / (lpart[0][row] + lpart[1][row]);
        }

    // epilogue: O /= l, write bf16 in [b][h*16+ov][t][f] layout
    const int h = hb >> 1, b = hb & 1;
#pragma unroll
    for (int dt = 0; dt < 8; ++dt) {
        int vcol = dsl + dt * 16 + c16;
        int cout = h * 16 + (vcol >> 6), ff = vcol & 63;
#pragma unroll
        for (int s4 = 0; s4 < 4; ++s4)
#pragma unroll
            for (int r = 0; r < 4; ++r) {
                int trow = t0 + s4 * 16 + g * 4 + r;
                Ob[(((size_t)b * 64 + cout) * 2048 + trow) * 64 + ff] =
                    f2bf(oacc[dt * 4 + s4][r] * li[s4 * 4 + r]);
            }
    }
}

// ---------------------------------------------------------------------------
// Kernel 4: output projection via MFMA + PReLU + LN(C,F) + residual
// ---------------------------------------------------------------------------
__global__ __launch_bounds__(256) void oproj_kernel(
    const short* __restrict__ Ob, const float* __restrict__ x,
    const short* __restrict__ Wpbf,
    const float* __restrict__ bp, const float* __restrict__ ap,
    const float* __restrict__ gp, const float* __restrict__ betp,
    float* __restrict__ out)
{
    const int t = blockIdx.x;
    const int b = blockIdx.y;
    const int tid = threadIdx.x;
    const int wid = tid >> 6, lane = tid & 63;
    const int g = lane >> 4, c16 = lane & 15;
    const int f_ = tid & 63, cg = tid >> 6;

    __shared__ __align__(16) short wp[64 * 64];
    __shared__ __align__(16) short os[64 * 64];
    __shared__ float zs[64 * 64];
    __shared__ float red[4][2];

#pragma unroll
    for (int j = 0; j < 2; ++j) {
        int i8 = tid + 256 * j;
        int row = i8 >> 3, cb = i8 & 7;
        s16x8 v = *(const s16x8*)(Wpbf + i8 * 8);
        *(s16x8*)&wp[row * 64 + ((cb ^ (row & 7)) * 8)] = v;
    }
#pragma unroll
    for (int it = 0; it < 2; ++it) {
        int cb = cg + 4 * it, c0 = cb * 8;
        s16x8 v;
#pragma unroll
        for (int i = 0; i < 8; ++i)
            v[i] = Ob[(((size_t)b * 64 + c0 + i) * 2048 + t) * 64 + f_];
        *(s16x8*)&os[f_ * 64 + ((cb ^ (f_ & 7)) * 8)] = v;
    }
    __syncthreads();

    const int f0 = wid * 16;
    s16x8 bfr[2];
#pragma unroll
    for (int kk = 0; kk < 2; ++kk)
        bfr[kk] = *(const s16x8*)&os[(f0 + c16) * 64 + (((kk * 4 + g) ^ (c16 & 7)) * 8)];

    const float ap0 = ap[0];
    f32x4 acc[4];
#pragma unroll
    for (int rt = 0; rt < 4; ++rt) {
#pragma unroll
        for (int r = 0; r < 4; ++r) acc[rt][r] = 0.f;
#pragma unroll
        for (int kk = 0; kk < 2; ++kk) {
            s16x8 a = *(const s16x8*)&wp[(rt * 16 + c16) * 64 + (((kk * 4 + g) ^ (c16 & 7)) * 8)];
            acc[rt] = __builtin_amdgcn_mfma_f32_16x16x32_bf16(a, bfr[kk], acc[rt], 0, 0, 0);
        }
    }

#pragma unroll
    for (int rt = 0; rt < 4; ++rt)
#pragma unroll
        for (int r = 0; r < 4; ++r) {
            int row = rt * 16 + g * 4 + r;
            float z = acc[rt][r] + bp[row];
            z = z >= 0.f ? z : ap0 * z;
            zs[row * 64 + f0 + c16] = z;
        }
    __syncthreads();

    float s = 0.f, ss = 0.f;
#pragma unroll
    for (int j = 0; j < 16; ++j) {
        float v = zs[(cg + 4 * j) * 64 + f_];
        s += v; ss += v * v;
    }
#pragma unroll
    for (int msk = 32; msk >= 1; msk >>= 1) {
        s  += __shfl_xor(s, msk);
        ss += __shfl_xor(ss, msk);
    }
    if (lane == 0) { red[wid][0] = s; red[wid][1] = ss; }
    __syncthreads();
    float ts  = red[0][0] + red[1][0] + red[2][0] + red[3][0];
    float tss = red[0][1] + red[1][1] + red[2][1] + red[3][1];
    float mean = ts * (1.f / 4096.f);
    float rstd = rsqrtf(tss * (1.f / 4096.f) - mean * mean + EPS_);

#pragma unroll
    for (int j = 0; j < 16; ++j) {
        int row = cg + 4 * j;
        size_t idx = (((size_t)b * 64 + row) * 2048 + t) * 64 + f_;
        out[idx] = (zs[row * 64 + f_] - mean) * rstd * gp[row * 64 + f_]
                 + betp[row * 64 + f_] + x[idx];
    }
}

// ---------------------------------------------------------------------------
extern "C" void kernel_launch(void* const* d_in, const int* in_sizes, int n_in,
                              void* d_out, int out_size, void* d_ws, size_t ws_size,
                              hipStream_t stream)
{
    const float* x    = (const float*)d_in[0];
    const float* Wq   = (const float*)d_in[1];
    const float* bq   = (const float*)d_in[2];
    const float* aq   = (const float*)d_in[3];
    const float* gq   = (const float*)d_in[4];
    const float* betq = (const float*)d_in[5];
    const float* Wk   = (const float*)d_in[6];
    const float* bk   = (const float*)d_in[7];
    const float* ak   = (const float*)d_in[8];
    const float* gk   = (const float*)d_in[9];
    const float* betk = (const float*)d_in[10];
    const float* Wv   = (const float*)d_in[11];
    const float* bv   = (const float*)d_in[12];
    const float* av   = (const float*)d_in[13];
    const float* gv   = (const float*)d_in[14];
    const float* betv = (const float*)d_in[15];
    const float* Wp   = (const float*)d_in[16];
    const float* bp   = (const float*)d_in[17];
    const float* ap   = (const float*)d_in[18];
    const float* gp   = (const float*)d_in[19];
    const float* betp = (const float*)d_in[20];

    short* Qb   = (short*)d_ws;
    short* Kb   = Qb   + (size_t)8 * 2048 * 256;
    short* Vrm  = Kb   + (size_t)8 * 2048 * 256;
    short* Vt   = Vrm  + (size_t)8 * 2048 * 1024;
    short* Obuf = Vt   + (size_t)8 * 2048 * 1024;
    short* Wbf  = Obuf + (size_t)8 * 2048 * 1024;
    short* Wpbf = Wbf  + 96 * 64;

    prep_kernel<<<40, 256, 0, stream>>>(Wq, Wk, Wv, Wp, Wbf, Wpbf);
    qkv_kernel<<<dim3(2048, 2), 256, 0, stream>>>(x, Wbf,
        bq, aq, gq, betq, bk, ak, gk, betk, bv, av, gv, betv, Qb, Kb, Vrm);
    vtrans_kernel<<<dim3(32, 16, 8), 256, 0, stream>>>(Vrm, Vt);
    attn_kernel<<<dim3(8, 32), 512, 0, stream>>>(Qb, Kb, Vt, Obuf);
    oproj_kernel<<<dim3(2048, 2), 256, 0, stream>>>(Obuf, x, Wpbf,
        bp, ap, gp, betp, (float*)d_out);
}